// Round 1
// baseline (105.729 us; speedup 1.0000x reference)
//
#include <hip/hip_runtime.h>

#define EPS 1e-5f
#define NROW 768
#define LOGITS_N (768 * 768)

// mish(z) = z * tanh(softplus(z)); with t = e^z:
// tanh(log(1+t)) = ((1+t)^2 - 1)/((1+t)^2 + 1) = t(t+2) / (t(t+2)+2)
__device__ __forceinline__ float mishf(float z) {
    float t = __expf(fminf(z, 40.f));
    float u = t * (t + 2.f);
    return z * u * __builtin_amdgcn_rcpf(u + 2.f);
}

// block of 256 threads (4 waves); returns full sum to all threads
__device__ __forceinline__ float block_sum(float v, float* red) {
#pragma unroll
    for (int off = 32; off > 0; off >>= 1) v += __shfl_down(v, off, 64);
    const int lane = threadIdx.x & 63, wid = threadIdx.x >> 6;
    __syncthreads();
    if (lane == 0) red[wid] = v;
    __syncthreads();
    return red[0] + red[1] + red[2] + red[3];
}

// One block per row i: X0 = h@W0+b0 -> LN(g0,be0) -> mish -> H=@W1+b1
// fi = H@Wc1[:128], fjb = H@Wc1[128:] + bc1, plus per-row mean/meansq stats.
__global__ __launch_bounds__(256) void k1_rows(
    const float* __restrict__ h, const float* __restrict__ W0,
    const float* __restrict__ b0, const float* __restrict__ g0,
    const float* __restrict__ be0, const float* __restrict__ W1,
    const float* __restrict__ b1, const float* __restrict__ Wc1,
    const float* __restrict__ bc1, float* __restrict__ fi,
    float* __restrict__ fjb, float* __restrict__ stats) {
    __shared__ float sh[256];
    __shared__ float sa[256];
    __shared__ float sH[128];
    __shared__ float red[4];
    const int i = blockIdx.x, j = threadIdx.x;
    sh[j] = h[i * 256 + j];
    __syncthreads();
    float x = b0[j];
#pragma unroll 8
    for (int k = 0; k < 256; ++k) x = fmaf(sh[k], W0[k * 256 + j], x);
    float s1 = block_sum(x, red);
    float s2 = block_sum(x * x, red);
    float mean = s1 * (1.f / 256.f);
    float var = fmaxf(s2 * (1.f / 256.f) - mean * mean, 0.f);
    float rs = __builtin_amdgcn_rsqf(var + EPS);
    float a = mishf((x - mean) * rs * g0[j] + be0[j]);
    sa[j] = a;
    __syncthreads();
    if (j < 128) {
        float hv = b1[j];
#pragma unroll 8
        for (int k = 0; k < 256; ++k) hv = fmaf(sa[k], W1[k * 128 + j], hv);
        sH[j] = hv;
    }
    __syncthreads();
    float vi = 0.f, vj = bc1[j];
#pragma unroll 8
    for (int k = 0; k < 128; ++k) {
        float hk = sH[k];
        vi = fmaf(hk, Wc1[k * 256 + j], vi);
        vj = fmaf(hk, Wc1[(128 + k) * 256 + j], vj);
    }
    fi[i * 256 + j] = vi;
    fjb[i * 256 + j] = vj;
    float su_i = block_sum(vi, red);
    float sq_i = block_sum(vi * vi, red);
    float su_j = block_sum(vj, red);
    float sq_j = block_sum(vj * vj, red);
    if (j == 0) {
        stats[i * 4 + 0] = su_i * (1.f / 256.f);
        stats[i * 4 + 1] = sq_i * (1.f / 256.f);
        stats[i * 4 + 2] = su_j * (1.f / 256.f);
        stats[i * 4 + 3] = sq_j * (1.f / 256.f);
    }
}

// cross[i][j] = dot(fi[i,:], fjb[j,:])  (768x768x256 f32 GEMM)
__global__ __launch_bounds__(256) void k2_cross(
    const float* __restrict__ fi, const float* __restrict__ fjb,
    float* __restrict__ cross) {
    __shared__ float A[32][68];  // [k][m], row stride 272B (16B-aligned)
    __shared__ float B[32][68];  // [k][n]
    const int tx = threadIdx.x, ty = threadIdx.y;
    const int tid = ty * 16 + tx;
    const int i0 = blockIdx.y * 64, j0 = blockIdx.x * 64;
    float acc[4][4] = {};
    for (int k0 = 0; k0 < 256; k0 += 32) {
#pragma unroll
        for (int l = 0; l < 2; ++l) {
            int idx = tid + l * 256;  // 0..511
            int m = idx >> 3;         // 0..63
            int kq = idx & 7;         // float4 index within 32 k's
            float4 va = *(const float4*)&fi[(i0 + m) * 256 + k0 + kq * 4];
            A[kq * 4 + 0][m] = va.x; A[kq * 4 + 1][m] = va.y;
            A[kq * 4 + 2][m] = va.z; A[kq * 4 + 3][m] = va.w;
            float4 vb = *(const float4*)&fjb[(j0 + m) * 256 + k0 + kq * 4];
            B[kq * 4 + 0][m] = vb.x; B[kq * 4 + 1][m] = vb.y;
            B[kq * 4 + 2][m] = vb.z; B[kq * 4 + 3][m] = vb.w;
        }
        __syncthreads();
#pragma unroll 8
        for (int kk = 0; kk < 32; ++kk) {
            float4 a4 = *(const float4*)&A[kk][ty * 4];
            float4 b4 = *(const float4*)&B[kk][tx * 4];
            float ar[4] = {a4.x, a4.y, a4.z, a4.w};
            float br[4] = {b4.x, b4.y, b4.z, b4.w};
#pragma unroll
            for (int r = 0; r < 4; ++r)
#pragma unroll
                for (int c = 0; c < 4; ++c)
                    acc[r][c] = fmaf(ar[r], br[c], acc[r][c]);
        }
        __syncthreads();
    }
#pragma unroll
    for (int r = 0; r < 4; ++r) {
        float4 o = {acc[r][0], acc[r][1], acc[r][2], acc[r][3]};
        *(float4*)&cross[(i0 + ty * 4 + r) * 768 + j0 + tx * 4] = o;
    }
}

// Per pair (i,j): LN stats from precomputed row stats + cross term, then
// single pass: logits[i,j] = sum_d mish((x-m)*rs*gc[d]+bec[d]) * Wc2[d] + bc2
__global__ __launch_bounds__(256) void k3_pair(
    const float* __restrict__ fi, const float* __restrict__ fjb,
    const float* __restrict__ cross, const float* __restrict__ stats,
    const float* __restrict__ gc, const float* __restrict__ bec,
    const float* __restrict__ wc2, const float* __restrict__ bc2,
    float* __restrict__ out, int write_mask) {
    __shared__ float FI[16][260];  // 260: row stride 1040B, 16B-aligned, bank-spread
    __shared__ float FJ[16][260];
    const int tid = threadIdx.x;
    const int i0 = blockIdx.y * 16, j0 = blockIdx.x * 16;
#pragma unroll
    for (int l = 0; l < 4; ++l) {
        int idx = tid + l * 256;     // 0..1023 float4 slots
        int r = idx >> 6, c = (idx & 63) * 4;
        *(float4*)&FI[r][c] = *(const float4*)&fi[(i0 + r) * 256 + c];
        *(float4*)&FJ[r][c] = *(const float4*)&fjb[(j0 + r) * 256 + c];
    }
    const int ti = tid >> 4, tj = tid & 15;
    float a_i = stats[(i0 + ti) * 4 + 0];
    float s_i = stats[(i0 + ti) * 4 + 1];
    float b_j = stats[(j0 + tj) * 4 + 2];
    float t_j = stats[(j0 + tj) * 4 + 3];
    float cij = cross[(i0 + ti) * 768 + (j0 + tj)];
    float m = a_i + b_j;
    float ex2 = s_i + t_j + cij * (2.f / 256.f);
    float var = fmaxf(ex2 - m * m, 0.f);
    float rs = __builtin_amdgcn_rsqf(var + EPS);
    float c0 = -m * rs;
    __syncthreads();
    float acc = 0.f;
#pragma unroll 8
    for (int d4 = 0; d4 < 64; ++d4) {
        float4 xi = *(const float4*)&FI[ti][d4 * 4];
        float4 xj = *(const float4*)&FJ[tj][d4 * 4];
        float4 g4 = *(const float4*)&gc[d4 * 4];    // uniform -> s_load
        float4 e4 = *(const float4*)&bec[d4 * 4];
        float4 w4 = *(const float4*)&wc2[d4 * 4];
        float xs[4] = {xi.x + xj.x, xi.y + xj.y, xi.z + xj.z, xi.w + xj.w};
        float gs[4] = {g4.x, g4.y, g4.z, g4.w};
        float es[4] = {e4.x, e4.y, e4.z, e4.w};
        float vs[4] = {w4.x, w4.y, w4.z, w4.w};
#pragma unroll
        for (int c = 0; c < 4; ++c) {
            float z = fmaf(xs[c], rs, c0);
            z = fmaf(z, gs[c], es[c]);
            float t = __expf(fminf(z, 40.f));
            float u = t * (t + 2.f);
            float w = u * __builtin_amdgcn_rcpf(u + 2.f);
            acc = fmaf(z * w, vs[c], acc);
        }
    }
    const int oi = (i0 + ti) * 768 + j0 + tj;
    out[oi] = acc + bc2[0];
    if (write_mask) out[LOGITS_N + oi] = 1.0f;  // matrix_mask = ones
}

extern "C" void kernel_launch(void* const* d_in, const int* in_sizes, int n_in,
                              void* d_out, int out_size, void* d_ws, size_t ws_size,
                              hipStream_t stream) {
    const float* h   = (const float*)d_in[0];
    const float* W0  = (const float*)d_in[1];
    const float* b0  = (const float*)d_in[2];
    const float* g0  = (const float*)d_in[3];
    const float* be0 = (const float*)d_in[4];
    const float* W1  = (const float*)d_in[5];
    const float* b1  = (const float*)d_in[6];
    const float* Wc1 = (const float*)d_in[7];
    const float* bc1 = (const float*)d_in[8];
    const float* gc  = (const float*)d_in[9];
    const float* bec = (const float*)d_in[10];
    const float* Wc2 = (const float*)d_in[11];
    const float* bc2 = (const float*)d_in[12];
    float* ws = (float*)d_ws;
    float* fi    = ws;             // 768*256
    float* fjb   = ws + 196608;    // 768*256
    float* stats = ws + 393216;    // 768*4
    float* cross = ws + 396288;    // 768*768
    float* out = (float*)d_out;
    int write_mask = (out_size >= 2 * LOGITS_N) ? 1 : 0;

    k1_rows<<<dim3(768), dim3(256), 0, stream>>>(h, W0, b0, g0, be0, W1, b1,
                                                 Wc1, bc1, fi, fjb, stats);
    k2_cross<<<dim3(12, 12), dim3(16, 16), 0, stream>>>(fi, fjb, cross);
    k3_pair<<<dim3(48, 48), dim3(256), 0, stream>>>(fi, fjb, cross, stats, gc,
                                                    bec, Wc2, bc2, out, write_mask);
}

// Round 2
// 91.957 us; speedup vs baseline: 1.1498x; 1.1498x over previous
//
#include <hip/hip_runtime.h>

#define EPS 1e-5f
#define LOGITS_N (768 * 768)
#define LOG2E 1.4426950408889634f
#define LN2   0.6931471805599453f

// mish(z) = z * tanh(softplus(z)); with t = e^z: mish = z*u/(u+2), u = t(t+2)
__device__ __forceinline__ float mishf(float z) {
    float t = __expf(fminf(z, 40.f));
    float u = t * (t + 2.f);
    return z * u * __builtin_amdgcn_rcpf(u + 2.f);
}

// block of 256 threads (4 waves); returns full sum to all threads
__device__ __forceinline__ float block_sum(float v, float* red) {
#pragma unroll
    for (int off = 32; off > 0; off >>= 1) v += __shfl_down(v, off, 64);
    const int lane = threadIdx.x & 63, wid = threadIdx.x >> 6;
    __syncthreads();
    if (lane == 0) red[wid] = v;
    __syncthreads();
    return red[0] + red[1] + red[2] + red[3];
}

// 4 rows per block: X0 = h@W0+b0 -> LN(g0,be0) -> mish -> H=@W1+b1
// fi = H@Wc1[:128], fjb = H@Wc1[128:] + bc1, plus per-row mean/meansq stats.
__global__ __launch_bounds__(256) void k1_rows(
    const float* __restrict__ h, const float* __restrict__ W0,
    const float* __restrict__ b0, const float* __restrict__ g0,
    const float* __restrict__ be0, const float* __restrict__ W1,
    const float* __restrict__ b1, const float* __restrict__ Wc1,
    const float* __restrict__ bc1, float* __restrict__ fi,
    float* __restrict__ fjb, float* __restrict__ stats) {
    __shared__ float sh[4][256];
    __shared__ float sa[4][256];
    __shared__ float sH[4][128];
    __shared__ float red[4];
    const int i0 = blockIdx.x * 4, j = threadIdx.x;
#pragma unroll
    for (int r = 0; r < 4; ++r) sh[r][j] = h[(i0 + r) * 256 + j];
    __syncthreads();
    float b0j = b0[j];
    float x[4] = {b0j, b0j, b0j, b0j};
#pragma unroll 4
    for (int k = 0; k < 256; ++k) {
        float w = W0[k * 256 + j];
#pragma unroll
        for (int r = 0; r < 4; ++r) x[r] = fmaf(sh[r][k], w, x[r]);
    }
    float g0j = g0[j], be0j = be0[j];
#pragma unroll
    for (int r = 0; r < 4; ++r) {
        float s1 = block_sum(x[r], red);
        float s2 = block_sum(x[r] * x[r], red);
        float mean = s1 * (1.f / 256.f);
        float var = fmaxf(s2 * (1.f / 256.f) - mean * mean, 0.f);
        float rs = __builtin_amdgcn_rsqf(var + EPS);
        sa[r][j] = mishf((x[r] - mean) * rs * g0j + be0j);
    }
    __syncthreads();
    if (j < 128) {
        float b1j = b1[j];
        float hv[4] = {b1j, b1j, b1j, b1j};
#pragma unroll 4
        for (int k = 0; k < 256; ++k) {
            float w = W1[k * 128 + j];
#pragma unroll
            for (int r = 0; r < 4; ++r) hv[r] = fmaf(sa[r][k], w, hv[r]);
        }
#pragma unroll
        for (int r = 0; r < 4; ++r) sH[r][j] = hv[r];
    }
    __syncthreads();
    float bc1j = bc1[j];
    float vi[4] = {0.f, 0.f, 0.f, 0.f};
    float vj[4] = {bc1j, bc1j, bc1j, bc1j};
#pragma unroll 4
    for (int k = 0; k < 128; ++k) {
        float wa = Wc1[k * 256 + j];
        float wb = Wc1[(128 + k) * 256 + j];
#pragma unroll
        for (int r = 0; r < 4; ++r) {
            float hk = sH[r][k];
            vi[r] = fmaf(hk, wa, vi[r]);
            vj[r] = fmaf(hk, wb, vj[r]);
        }
    }
#pragma unroll
    for (int r = 0; r < 4; ++r) {
        fi[(i0 + r) * 256 + j] = vi[r];
        fjb[(i0 + r) * 256 + j] = vj[r];
    }
#pragma unroll
    for (int r = 0; r < 4; ++r) {
        float su_i = block_sum(vi[r], red);
        float sq_i = block_sum(vi[r] * vi[r], red);
        float su_j = block_sum(vj[r], red);
        float sq_j = block_sum(vj[r] * vj[r], red);
        if (j == 0) {
            stats[(i0 + r) * 4 + 0] = su_i * (1.f / 256.f);
            stats[(i0 + r) * 4 + 1] = sq_i * (1.f / 256.f);
            stats[(i0 + r) * 4 + 2] = su_j * (1.f / 256.f);
            stats[(i0 + r) * 4 + 3] = sq_j * (1.f / 256.f);
        }
    }
}

// Per pair (i,j): in-thread cross dot -> LN stats -> single mish+dot pass.
// exp2-domain: y = z*log2e; t = 2^y = e^z; mish = z - 2z/(t^2+2t+2);
// acc += mish*wc2 = (y - 2yr)*(wc2*ln2). Prefolded: G'=gc*log2e, E'=bec*log2e,
// W'=wc2*ln2. Inf-safe: t=inf -> r=0 -> mish=z; t=0 -> r=.5 -> mish=0.
__global__ __launch_bounds__(256) void k3_pair(
    const float* __restrict__ fi, const float* __restrict__ fjb,
    const float* __restrict__ stats,
    const float* __restrict__ gc, const float* __restrict__ bec,
    const float* __restrict__ wc2, const float* __restrict__ bc2,
    float* __restrict__ out, int write_mask) {
    __shared__ float FI[16][260];  // stride 1040B: 16B-aligned, 2-way banks (free)
    __shared__ float FJ[16][260];
    __shared__ float Gs[256], Es[256], Ws[256];
    const int tid = threadIdx.x;
    const int i0 = blockIdx.y * 16, j0 = blockIdx.x * 16;
#pragma unroll
    for (int l = 0; l < 4; ++l) {
        int idx = tid + l * 256;     // 0..1023 float4 slots
        int r = idx >> 6, c = (idx & 63) * 4;
        *(float4*)&FI[r][c] = *(const float4*)&fi[(i0 + r) * 256 + c];
        *(float4*)&FJ[r][c] = *(const float4*)&fjb[(j0 + r) * 256 + c];
    }
    Gs[tid] = gc[tid] * LOG2E;
    Es[tid] = bec[tid] * LOG2E;
    Ws[tid] = wc2[tid] * LN2;
    const int ti = tid >> 4, tj = tid & 15;
    float a_i = stats[(i0 + ti) * 4 + 0];
    float s_i = stats[(i0 + ti) * 4 + 1];
    float b_j = stats[(j0 + tj) * 4 + 2];
    float t_j = stats[(j0 + tj) * 4 + 3];
    __syncthreads();
    const float* FIp = &FI[ti][0];
    const float* FJp = &FJ[tj][0];
    // pass 1: dot(fi[i], fjb[j]) for the LN cross term
    float dot[4] = {0.f, 0.f, 0.f, 0.f};
#pragma unroll 8
    for (int d4 = 0; d4 < 64; ++d4) {
        float4 xi = *(const float4*)&FIp[d4 * 4];
        float4 xj = *(const float4*)&FJp[d4 * 4];
        dot[0] = fmaf(xi.x, xj.x, dot[0]);
        dot[1] = fmaf(xi.y, xj.y, dot[1]);
        dot[2] = fmaf(xi.z, xj.z, dot[2]);
        dot[3] = fmaf(xi.w, xj.w, dot[3]);
    }
    float m = a_i + b_j;
    float ex2 = s_i + t_j + (dot[0] + dot[1] + dot[2] + dot[3]) * (2.f / 256.f);
    float var = fmaxf(ex2 - m * m, 0.f);
    float rs = __builtin_amdgcn_rsqf(var + EPS);
    float c0 = -m * rs;
    // pass 2: logits[i,j]
    float acc[4] = {0.f, 0.f, 0.f, 0.f};
#pragma unroll 8
    for (int d4 = 0; d4 < 64; ++d4) {
        float4 xi = *(const float4*)&FIp[d4 * 4];
        float4 xj = *(const float4*)&FJp[d4 * 4];
        float4 g4 = *(const float4*)&Gs[d4 * 4];  // uniform addr -> broadcast
        float4 e4 = *(const float4*)&Es[d4 * 4];
        float4 w4 = *(const float4*)&Ws[d4 * 4];
        float xs[4] = {xi.x + xj.x, xi.y + xj.y, xi.z + xj.z, xi.w + xj.w};
        float gs[4] = {g4.x, g4.y, g4.z, g4.w};
        float es[4] = {e4.x, e4.y, e4.z, e4.w};
        float vs[4] = {w4.x, w4.y, w4.z, w4.w};
#pragma unroll
        for (int c = 0; c < 4; ++c) {
            float p = fmaf(xs[c], rs, c0);              // (x - m) * rs
            float y = fmaf(p, gs[c], es[c]);            // z * log2e
            float t = __builtin_amdgcn_exp2f(y);        // e^z
            float v = fmaf(t, t + 2.f, 2.f);            // t^2+2t+2
            float r = __builtin_amdgcn_rcpf(v);
            float my = fmaf(y * r, -2.f, y);            // y*(1-2/v)
            acc[c] = fmaf(my, vs[c], acc[c]);           // * wc2*ln2
        }
    }
    const int oi = (i0 + ti) * 768 + j0 + tj;
    out[oi] = (acc[0] + acc[1]) + (acc[2] + acc[3]) + bc2[0];
    if (write_mask) out[LOGITS_N + oi] = 1.0f;  // matrix_mask = ones
}

extern "C" void kernel_launch(void* const* d_in, const int* in_sizes, int n_in,
                              void* d_out, int out_size, void* d_ws, size_t ws_size,
                              hipStream_t stream) {
    const float* h   = (const float*)d_in[0];
    const float* W0  = (const float*)d_in[1];
    const float* b0  = (const float*)d_in[2];
    const float* g0  = (const float*)d_in[3];
    const float* be0 = (const float*)d_in[4];
    const float* W1  = (const float*)d_in[5];
    const float* b1  = (const float*)d_in[6];
    const float* Wc1 = (const float*)d_in[7];
    const float* bc1 = (const float*)d_in[8];
    const float* gc  = (const float*)d_in[9];
    const float* bec = (const float*)d_in[10];
    const float* Wc2 = (const float*)d_in[11];
    const float* bc2 = (const float*)d_in[12];
    float* ws = (float*)d_ws;
    float* fi    = ws;             // 768*256
    float* fjb   = ws + 196608;    // 768*256
    float* stats = ws + 393216;    // 768*4
    float* out = (float*)d_out;
    int write_mask = (out_size >= 2 * LOGITS_N) ? 1 : 0;

    k1_rows<<<dim3(192), dim3(256), 0, stream>>>(h, W0, b0, g0, be0, W1, b1,
                                                 Wc1, bc1, fi, fjb, stats);
    k3_pair<<<dim3(48, 48), dim3(256), 0, stream>>>(fi, fjb, stats, gc,
                                                    bec, Wc2, bc2, out, write_mask);
}

// Round 3
// 76.493 us; speedup vs baseline: 1.3822x; 1.2022x over previous
//
#include <hip/hip_runtime.h>

#define EPS 1e-5f
#define LOGITS_N (768 * 768)
#define LOG2E 1.4426950408889634f
#define LN2   0.6931471805599453f

// mish(z) = z * tanh(softplus(z)); with t = e^z: mish = z*u/(u+2), u = t(t+2)
__device__ __forceinline__ float mishf(float z) {
    float t = __expf(fminf(z, 40.f));
    float u = t * (t + 2.f);
    return z * u * __builtin_amdgcn_rcpf(u + 2.f);
}

// block of 256 threads (4 waves); returns full sum to all threads
__device__ __forceinline__ float block_sum(float v, float* red) {
#pragma unroll
    for (int off = 32; off > 0; off >>= 1) v += __shfl_down(v, off, 64);
    const int lane = threadIdx.x & 63, wid = threadIdx.x >> 6;
    __syncthreads();
    if (lane == 0) red[wid] = v;
    __syncthreads();
    return red[0] + red[1] + red[2] + red[3];
}

// 2 rows per block (384 blocks). All weight loads are coalesced float4 via
// k-split thread groups; partials reduced through a padded LDS buffer
// (12-float slots: 16B-aligned, <=2-way banks on reads).
__global__ __launch_bounds__(256) void k1_rows(
    const float* __restrict__ h, const float* __restrict__ W0,
    const float* __restrict__ b0, const float* __restrict__ g0,
    const float* __restrict__ be0, const float* __restrict__ W1,
    const float* __restrict__ b1, const float* __restrict__ Wc1,
    const float* __restrict__ bc1, const float* __restrict__ gc,
    const float* __restrict__ bec, const float* __restrict__ wc2,
    float* __restrict__ fi, float* __restrict__ fjb,
    float* __restrict__ stats, float* __restrict__ Gp,
    float* __restrict__ Ep, float* __restrict__ Wp) {
    __shared__ float shi[256][2];
    __shared__ float sai[256][2];
    __shared__ float sHi[128][2];
    __shared__ float red[4];
    __shared__ float part[4][64][12];  // 12 KiB, reused by every GEMM phase
    const int t = threadIdx.x;
    const int i0 = blockIdx.x * 2;
    if (blockIdx.x == 0) {  // prescaled per-d arrays for k3 (scalar-load path)
        Gp[t] = gc[t] * LOG2E;
        Ep[t] = bec[t] * LOG2E;
        Wp[t] = wc2[t] * LN2;
    }
    shi[t][0] = h[i0 * 256 + t];
    shi[t][1] = h[i0 * 256 + 256 + t];
    __syncthreads();
    // ---- GEMM1: x[2][256] = h2 @ W0   (k-split 4 x 64, cols 4/thread) ----
    {
        const int kc = t >> 6, jg = t & 63;
        const float* w0p = W0 + (kc * 64) * 256 + jg * 4;
        float ax[2][4] = {};
#pragma unroll 8
        for (int kk = 0; kk < 64; ++kk) {
            float4 w = *(const float4*)(w0p + kk * 256);
            float2 hh = *(const float2*)&shi[kc * 64 + kk][0];  // wave-uniform
            ax[0][0] = fmaf(hh.x, w.x, ax[0][0]);
            ax[0][1] = fmaf(hh.x, w.y, ax[0][1]);
            ax[0][2] = fmaf(hh.x, w.z, ax[0][2]);
            ax[0][3] = fmaf(hh.x, w.w, ax[0][3]);
            ax[1][0] = fmaf(hh.y, w.x, ax[1][0]);
            ax[1][1] = fmaf(hh.y, w.y, ax[1][1]);
            ax[1][2] = fmaf(hh.y, w.z, ax[1][2]);
            ax[1][3] = fmaf(hh.y, w.w, ax[1][3]);
        }
        float* pp = &part[kc][jg][0];
#pragma unroll
        for (int c = 0; c < 4; ++c) { pp[c * 2] = ax[0][c]; pp[c * 2 + 1] = ax[1][c]; }
    }
    __syncthreads();
    float x0, x1;
    {
        const int m = t >> 2, c = t & 3;
        x0 = b0[t]; x1 = x0;
#pragma unroll
        for (int kc = 0; kc < 4; ++kc) {
            x0 += part[kc][m][c * 2 + 0];
            x1 += part[kc][m][c * 2 + 1];
        }
    }
    // ---- LN + mish per row ----
    {
        float s1 = block_sum(x0, red), s2 = block_sum(x0 * x0, red);
        float mean = s1 * (1.f / 256.f);
        float var = fmaxf(s2 * (1.f / 256.f) - mean * mean, 0.f);
        float rs = __builtin_amdgcn_rsqf(var + EPS);
        sai[t][0] = mishf((x0 - mean) * rs * g0[t] + be0[t]);
        s1 = block_sum(x1, red); s2 = block_sum(x1 * x1, red);
        mean = s1 * (1.f / 256.f);
        var = fmaxf(s2 * (1.f / 256.f) - mean * mean, 0.f);
        rs = __builtin_amdgcn_rsqf(var + EPS);
        sai[t][1] = mishf((x1 - mean) * rs * g0[t] + be0[t]);
    }
    __syncthreads();
    // ---- GEMM2: H[2][128] = a2 @ W1   (k-split 8 x 32, cols 4/thread) ----
    {
        const int kc = t >> 5, jg = t & 31;
        const float* w1p = W1 + (kc * 32) * 128 + jg * 4;
        float ah[2][4] = {};
#pragma unroll 8
        for (int kk = 0; kk < 32; ++kk) {
            float4 w = *(const float4*)(w1p + kk * 128);
            float2 ss = *(const float2*)&sai[kc * 32 + kk][0];
            ah[0][0] = fmaf(ss.x, w.x, ah[0][0]);
            ah[0][1] = fmaf(ss.x, w.y, ah[0][1]);
            ah[0][2] = fmaf(ss.x, w.z, ah[0][2]);
            ah[0][3] = fmaf(ss.x, w.w, ah[0][3]);
            ah[1][0] = fmaf(ss.y, w.x, ah[1][0]);
            ah[1][1] = fmaf(ss.y, w.y, ah[1][1]);
            ah[1][2] = fmaf(ss.y, w.z, ah[1][2]);
            ah[1][3] = fmaf(ss.y, w.w, ah[1][3]);
        }
        float* pp = &part[0][0][0] + (kc * 32 + jg) * 12;
#pragma unroll
        for (int c = 0; c < 4; ++c) { pp[c * 2] = ah[0][c]; pp[c * 2 + 1] = ah[1][c]; }
    }
    __syncthreads();
    {
        const int r = t >> 7, jj = t & 127;
        float hv = b1[jj];
        const float* pf = &part[0][0][0];
#pragma unroll
        for (int kc = 0; kc < 8; ++kc)
            hv += pf[(kc * 32 + (jj >> 2)) * 12 + (jj & 3) * 2 + r];
        sHi[jj][r] = hv;
    }
    __syncthreads();
    // ---- GEMM3: vi = H@Wi, vj = H@Wj (K=128, k-split 4 x 32, cols 4/th) ----
    float avi[2][4] = {}, avj[2][4] = {};
    {
        const int kc = t >> 6, jg = t & 63;
        const float* wip = Wc1 + (kc * 32) * 256 + jg * 4;
        const float* wjp = Wc1 + (128 + kc * 32) * 256 + jg * 4;
#pragma unroll 4
        for (int kk = 0; kk < 32; ++kk) {
            float4 wa = *(const float4*)(wip + kk * 256);
            float4 wb = *(const float4*)(wjp + kk * 256);
            float2 hh = *(const float2*)&sHi[kc * 32 + kk][0];
            avi[0][0] = fmaf(hh.x, wa.x, avi[0][0]);
            avi[0][1] = fmaf(hh.x, wa.y, avi[0][1]);
            avi[0][2] = fmaf(hh.x, wa.z, avi[0][2]);
            avi[0][3] = fmaf(hh.x, wa.w, avi[0][3]);
            avi[1][0] = fmaf(hh.y, wa.x, avi[1][0]);
            avi[1][1] = fmaf(hh.y, wa.y, avi[1][1]);
            avi[1][2] = fmaf(hh.y, wa.z, avi[1][2]);
            avi[1][3] = fmaf(hh.y, wa.w, avi[1][3]);
            avj[0][0] = fmaf(hh.x, wb.x, avj[0][0]);
            avj[0][1] = fmaf(hh.x, wb.y, avj[0][1]);
            avj[0][2] = fmaf(hh.x, wb.z, avj[0][2]);
            avj[0][3] = fmaf(hh.x, wb.w, avj[0][3]);
            avj[1][0] = fmaf(hh.y, wb.x, avj[1][0]);
            avj[1][1] = fmaf(hh.y, wb.y, avj[1][1]);
            avj[1][2] = fmaf(hh.y, wb.z, avj[1][2]);
            avj[1][3] = fmaf(hh.y, wb.w, avj[1][3]);
        }
        float* pp = &part[kc][jg][0];
#pragma unroll
        for (int c = 0; c < 4; ++c) { pp[c * 2] = avi[0][c]; pp[c * 2 + 1] = avi[1][c]; }
    }
    __syncthreads();
    float vi0 = 0.f, vi1 = 0.f;
    {
        const int m = t >> 2, c = t & 3;
#pragma unroll
        for (int kc = 0; kc < 4; ++kc) {
            vi0 += part[kc][m][c * 2 + 0];
            vi1 += part[kc][m][c * 2 + 1];
        }
    }
    __syncthreads();
    {
        const int kc = t >> 6, jg = t & 63;
        float* pp = &part[kc][jg][0];
#pragma unroll
        for (int c = 0; c < 4; ++c) { pp[c * 2] = avj[0][c]; pp[c * 2 + 1] = avj[1][c]; }
    }
    __syncthreads();
    float vj0, vj1;
    {
        const int m = t >> 2, c = t & 3;
        vj0 = bc1[t]; vj1 = vj0;
#pragma unroll
        for (int kc = 0; kc < 4; ++kc) {
            vj0 += part[kc][m][c * 2 + 0];
            vj1 += part[kc][m][c * 2 + 1];
        }
    }
    fi[i0 * 256 + t] = vi0;
    fi[(i0 + 1) * 256 + t] = vi1;
    fjb[i0 * 256 + t] = vj0;
    fjb[(i0 + 1) * 256 + t] = vj1;
    {
        float su = block_sum(vi0, red), sq = block_sum(vi0 * vi0, red);
        float sv = block_sum(vj0, red), sw = block_sum(vj0 * vj0, red);
        if (t == 0) {
            stats[i0 * 4 + 0] = su * (1.f / 256.f);
            stats[i0 * 4 + 1] = sq * (1.f / 256.f);
            stats[i0 * 4 + 2] = sv * (1.f / 256.f);
            stats[i0 * 4 + 3] = sw * (1.f / 256.f);
        }
        su = block_sum(vi1, red); sq = block_sum(vi1 * vi1, red);
        sv = block_sum(vj1, red); sw = block_sum(vj1 * vj1, red);
        if (t == 0) {
            stats[(i0 + 1) * 4 + 0] = su * (1.f / 256.f);
            stats[(i0 + 1) * 4 + 1] = sq * (1.f / 256.f);
            stats[(i0 + 1) * 4 + 2] = sv * (1.f / 256.f);
            stats[(i0 + 1) * 4 + 3] = sw * (1.f / 256.f);
        }
    }
}

// Per pair (i,j): in-thread cross dot -> LN stats -> single mish+dot pass.
// exp2-domain; mish = z - 2z/(t^2+2t+2), t = e^z; inf-safe. 4 rcp's batched
// into 1 via reciprocal-of-product (v >= 2 always; overflow needs sum z+ > 44
// in a 4-group -- impossible for LN-normalized z). G' from LDS (VGPR operand),
// E'/W' from prescaled global via uniform index (s_load path, 1-SGPR rule ok).
__global__ __launch_bounds__(256) void k3_pair(
    const float* __restrict__ fi, const float* __restrict__ fjb,
    const float* __restrict__ stats, const float* __restrict__ Gp,
    const float* __restrict__ Ep, const float* __restrict__ Wp,
    const float* __restrict__ bc2, float* __restrict__ out, int write_mask) {
    __shared__ float FI[16][260];  // stride 1040B: 16B-aligned, 2-way banks
    __shared__ float FJ[16][260];
    __shared__ float Gs[256];
    const int tid = threadIdx.x;
    const int i0 = blockIdx.y * 16, j0 = blockIdx.x * 16;
#pragma unroll
    for (int l = 0; l < 4; ++l) {
        int idx = tid + l * 256;
        int r = idx >> 6, c = (idx & 63) * 4;
        *(float4*)&FI[r][c] = *(const float4*)&fi[(i0 + r) * 256 + c];
        *(float4*)&FJ[r][c] = *(const float4*)&fjb[(j0 + r) * 256 + c];
    }
    Gs[tid] = Gp[tid];
    const int ti = tid >> 4, tj = tid & 15;
    float a_i = stats[(i0 + ti) * 4 + 0];
    float s_i = stats[(i0 + ti) * 4 + 1];
    float b_j = stats[(j0 + tj) * 4 + 2];
    float t_j = stats[(j0 + tj) * 4 + 3];
    __syncthreads();
    const float* FIp = &FI[ti][0];
    const float* FJp = &FJ[tj][0];
    // pass 1: dot(fi[i], fjb[j]) for the LN cross term
    float dot[4] = {0.f, 0.f, 0.f, 0.f};
#pragma unroll 8
    for (int d4 = 0; d4 < 64; ++d4) {
        float4 xi = *(const float4*)&FIp[d4 * 4];
        float4 xj = *(const float4*)&FJp[d4 * 4];
        dot[0] = fmaf(xi.x, xj.x, dot[0]);
        dot[1] = fmaf(xi.y, xj.y, dot[1]);
        dot[2] = fmaf(xi.z, xj.z, dot[2]);
        dot[3] = fmaf(xi.w, xj.w, dot[3]);
    }
    float m = a_i + b_j;
    float ex2 = s_i + t_j + (dot[0] + dot[1] + dot[2] + dot[3]) * (2.f / 256.f);
    float var = fmaxf(ex2 - m * m, 0.f);
    float rs = __builtin_amdgcn_rsqf(var + EPS);
    float c0 = -m * rs;
    // pass 2
    const float4* Ep4 = (const float4*)Ep;
    const float4* Wp4 = (const float4*)Wp;
    float acc[4] = {0.f, 0.f, 0.f, 0.f};
#pragma unroll 8
    for (int d4 = 0; d4 < 64; ++d4) {
        float4 xi = *(const float4*)&FIp[d4 * 4];
        float4 xj = *(const float4*)&FJp[d4 * 4];
        float4 g4 = *(const float4*)&Gs[d4 * 4];  // uniform LDS -> broadcast
        float4 e4 = Ep4[d4];                      // uniform global -> s_load
        float4 w4 = Wp4[d4];
        float gs[4] = {g4.x, g4.y, g4.z, g4.w};
        float es[4] = {e4.x, e4.y, e4.z, e4.w};
        float vs[4] = {w4.x, w4.y, w4.z, w4.w};
        float xs[4] = {xi.x + xj.x, xi.y + xj.y, xi.z + xj.z, xi.w + xj.w};
        float y[4], v[4];
#pragma unroll
        for (int c = 0; c < 4; ++c) {
            float p = fmaf(xs[c], rs, c0);            // (x - m) * rs
            y[c] = fmaf(p, gs[c], es[c]);             // z * log2e
            float tt = __builtin_amdgcn_exp2f(y[c]);  // e^z
            v[c] = fmaf(tt, tt + 2.f, 2.f);           // t^2+2t+2  (>= 2)
        }
        float p01 = v[0] * v[1], p23 = v[2] * v[3];
        float rr = __builtin_amdgcn_rcpf(p01 * p23);
        float i01 = rr * p23, i23 = rr * p01;
        float inv[4] = {i01 * v[1], i01 * v[0], i23 * v[3], i23 * v[2]};
#pragma unroll
        for (int c = 0; c < 4; ++c) {
            float my = fmaf(y[c] * inv[c], -2.f, y[c]);  // y*(1-2/v)
            acc[c] = fmaf(my, vs[c], acc[c]);            // * wc2*ln2
        }
    }
    const int oi = (i0 + ti) * 768 + j0 + tj;
    out[oi] = (acc[0] + acc[1]) + (acc[2] + acc[3]) + bc2[0];
    if (write_mask) out[LOGITS_N + oi] = 1.0f;  // matrix_mask = ones
}

extern "C" void kernel_launch(void* const* d_in, const int* in_sizes, int n_in,
                              void* d_out, int out_size, void* d_ws, size_t ws_size,
                              hipStream_t stream) {
    const float* h   = (const float*)d_in[0];
    const float* W0  = (const float*)d_in[1];
    const float* b0  = (const float*)d_in[2];
    const float* g0  = (const float*)d_in[3];
    const float* be0 = (const float*)d_in[4];
    const float* W1  = (const float*)d_in[5];
    const float* b1  = (const float*)d_in[6];
    const float* Wc1 = (const float*)d_in[7];
    const float* bc1 = (const float*)d_in[8];
    const float* gc  = (const float*)d_in[9];
    const float* bec = (const float*)d_in[10];
    const float* Wc2 = (const float*)d_in[11];
    const float* bc2 = (const float*)d_in[12];
    float* ws = (float*)d_ws;
    float* fi    = ws;             // 768*256
    float* fjb   = ws + 196608;    // 768*256
    float* stats = ws + 393216;    // 768*4
    float* Gp    = ws + 396288;    // 256
    float* Ep    = ws + 396544;    // 256
    float* Wp    = ws + 396800;    // 256
    float* out = (float*)d_out;
    int write_mask = (out_size >= 2 * LOGITS_N) ? 1 : 0;

    k1_rows<<<dim3(384), dim3(256), 0, stream>>>(h, W0, b0, g0, be0, W1, b1,
                                                 Wc1, bc1, gc, bec, Wc2,
                                                 fi, fjb, stats, Gp, Ep, Wp);
    k3_pair<<<dim3(48, 48), dim3(256), 0, stream>>>(fi, fjb, stats, Gp, Ep, Wp,
                                                    bc2, out, write_mask);
}

// Round 4
// 68.154 us; speedup vs baseline: 1.5513x; 1.1224x over previous
//
#include <hip/hip_runtime.h>

#define EPS 1e-5f
#define LOGITS_N (768 * 768)
#define LOG2E 1.4426950408889634f
#define LN2   0.6931471805599453f

typedef float v2f __attribute__((ext_vector_type(2)));
typedef float v4f __attribute__((ext_vector_type(4)));

// Packed fp32 ops (VOP3P). Guaranteed packing via inline asm; operands are
// 64-bit VGPR pairs (even-aligned by the "v" constraint on an 8-byte type).
__device__ __forceinline__ v2f pk_add(v2f a, v2f b) {
    v2f d; asm("v_pk_add_f32 %0, %1, %2" : "=v"(d) : "v"(a), "v"(b)); return d;
}
__device__ __forceinline__ v2f pk_mul(v2f a, v2f b) {
    v2f d; asm("v_pk_mul_f32 %0, %1, %2" : "=v"(d) : "v"(a), "v"(b)); return d;
}
__device__ __forceinline__ v2f pk_fma(v2f a, v2f b, v2f c) {
    v2f d; asm("v_pk_fma_f32 %0, %1, %2, %3" : "=v"(d) : "v"(a), "v"(b), "v"(c)); return d;
}
#define LO2(v) __builtin_shufflevector(v, v, 0, 1)
#define HI2(v) __builtin_shufflevector(v, v, 2, 3)

// mish(z) = z * tanh(softplus(z)); with t = e^z: mish = z*u/(u+2), u = t(t+2)
__device__ __forceinline__ float mishf(float z) {
    float t = __expf(fminf(z, 40.f));
    float u = t * (t + 2.f);
    return z * u * __builtin_amdgcn_rcpf(u + 2.f);
}

// block of 256 threads (4 waves); returns full sum to all threads
__device__ __forceinline__ float block_sum(float v, float* red) {
#pragma unroll
    for (int off = 32; off > 0; off >>= 1) v += __shfl_down(v, off, 64);
    const int lane = threadIdx.x & 63, wid = threadIdx.x >> 6;
    __syncthreads();
    if (lane == 0) red[wid] = v;
    __syncthreads();
    return red[0] + red[1] + red[2] + red[3];
}

// 2 rows per block (384 blocks). Coalesced float4 weight loads via k-split;
// per-row stats now include Di = dot(fi, gc.*wc2), Dj = dot(fjb, gc.*wc2)
// for k3's linear-term offload. stats stride = 8 floats/row.
__global__ __launch_bounds__(256) void k1_rows(
    const float* __restrict__ h, const float* __restrict__ W0,
    const float* __restrict__ b0, const float* __restrict__ g0,
    const float* __restrict__ be0, const float* __restrict__ W1,
    const float* __restrict__ b1, const float* __restrict__ Wc1,
    const float* __restrict__ bc1, const float* __restrict__ gc,
    const float* __restrict__ bec, const float* __restrict__ wc2,
    float* __restrict__ fi, float* __restrict__ fjb,
    float* __restrict__ stats, float* __restrict__ Gp,
    float* __restrict__ Ep, float* __restrict__ Wp,
    float* __restrict__ consts) {
    __shared__ float shi[256][2];
    __shared__ float sai[256][2];
    __shared__ float sHi[128][2];
    __shared__ float red[4];
    __shared__ float part[4][64][12];
    const int t = threadIdx.x;
    const int i0 = blockIdx.x * 2;
    const float u = gc[t] * wc2[t];
    if (blockIdx.x == 0) {  // prescaled per-d arrays + global consts for k3
        Gp[t] = gc[t] * LOG2E;
        Ep[t] = bec[t] * LOG2E;
        Wp[t] = wc2[t] * LN2;
        float sgw = block_sum(u, red);
        float sew = block_sum(bec[t] * wc2[t], red);
        if (t == 0) { consts[0] = sgw; consts[1] = sew; }
    }
    shi[t][0] = h[i0 * 256 + t];
    shi[t][1] = h[i0 * 256 + 256 + t];
    __syncthreads();
    // ---- GEMM1: x[2][256] = h2 @ W0   (k-split 4 x 64, cols 4/thread) ----
    {
        const int kc = t >> 6, jg = t & 63;
        const float* w0p = W0 + (kc * 64) * 256 + jg * 4;
        float ax[2][4] = {};
#pragma unroll 8
        for (int kk = 0; kk < 64; ++kk) {
            float4 w = *(const float4*)(w0p + kk * 256);
            float2 hh = *(const float2*)&shi[kc * 64 + kk][0];
            ax[0][0] = fmaf(hh.x, w.x, ax[0][0]);
            ax[0][1] = fmaf(hh.x, w.y, ax[0][1]);
            ax[0][2] = fmaf(hh.x, w.z, ax[0][2]);
            ax[0][3] = fmaf(hh.x, w.w, ax[0][3]);
            ax[1][0] = fmaf(hh.y, w.x, ax[1][0]);
            ax[1][1] = fmaf(hh.y, w.y, ax[1][1]);
            ax[1][2] = fmaf(hh.y, w.z, ax[1][2]);
            ax[1][3] = fmaf(hh.y, w.w, ax[1][3]);
        }
        float* pp = &part[kc][jg][0];
#pragma unroll
        for (int c = 0; c < 4; ++c) { pp[c * 2] = ax[0][c]; pp[c * 2 + 1] = ax[1][c]; }
    }
    __syncthreads();
    float x0, x1;
    {
        const int m = t >> 2, c = t & 3;
        x0 = b0[t]; x1 = x0;
#pragma unroll
        for (int kc = 0; kc < 4; ++kc) {
            x0 += part[kc][m][c * 2 + 0];
            x1 += part[kc][m][c * 2 + 1];
        }
    }
    // ---- LN + mish per row ----
    {
        float s1 = block_sum(x0, red), s2 = block_sum(x0 * x0, red);
        float mean = s1 * (1.f / 256.f);
        float var = fmaxf(s2 * (1.f / 256.f) - mean * mean, 0.f);
        float rs = __builtin_amdgcn_rsqf(var + EPS);
        sai[t][0] = mishf((x0 - mean) * rs * g0[t] + be0[t]);
        s1 = block_sum(x1, red); s2 = block_sum(x1 * x1, red);
        mean = s1 * (1.f / 256.f);
        var = fmaxf(s2 * (1.f / 256.f) - mean * mean, 0.f);
        rs = __builtin_amdgcn_rsqf(var + EPS);
        sai[t][1] = mishf((x1 - mean) * rs * g0[t] + be0[t]);
    }
    __syncthreads();
    // ---- GEMM2: H[2][128] = a2 @ W1   (k-split 8 x 32, cols 4/thread) ----
    {
        const int kc = t >> 5, jg = t & 31;
        const float* w1p = W1 + (kc * 32) * 128 + jg * 4;
        float ah[2][4] = {};
#pragma unroll 8
        for (int kk = 0; kk < 32; ++kk) {
            float4 w = *(const float4*)(w1p + kk * 128);
            float2 ss = *(const float2*)&sai[kc * 32 + kk][0];
            ah[0][0] = fmaf(ss.x, w.x, ah[0][0]);
            ah[0][1] = fmaf(ss.x, w.y, ah[0][1]);
            ah[0][2] = fmaf(ss.x, w.z, ah[0][2]);
            ah[0][3] = fmaf(ss.x, w.w, ah[0][3]);
            ah[1][0] = fmaf(ss.y, w.x, ah[1][0]);
            ah[1][1] = fmaf(ss.y, w.y, ah[1][1]);
            ah[1][2] = fmaf(ss.y, w.z, ah[1][2]);
            ah[1][3] = fmaf(ss.y, w.w, ah[1][3]);
        }
        float* pp = &part[0][0][0] + (kc * 32 + jg) * 12;
#pragma unroll
        for (int c = 0; c < 4; ++c) { pp[c * 2] = ah[0][c]; pp[c * 2 + 1] = ah[1][c]; }
    }
    __syncthreads();
    {
        const int r = t >> 7, jj = t & 127;
        float hv = b1[jj];
        const float* pf = &part[0][0][0];
#pragma unroll
        for (int kc = 0; kc < 8; ++kc)
            hv += pf[(kc * 32 + (jj >> 2)) * 12 + (jj & 3) * 2 + r];
        sHi[jj][r] = hv;
    }
    __syncthreads();
    // ---- GEMM3: vi = H@Wi, vj = H@Wj (K=128, k-split 4 x 32) ----
    float avi[2][4] = {}, avj[2][4] = {};
    {
        const int kc = t >> 6, jg = t & 63;
        const float* wip = Wc1 + (kc * 32) * 256 + jg * 4;
        const float* wjp = Wc1 + (128 + kc * 32) * 256 + jg * 4;
#pragma unroll 4
        for (int kk = 0; kk < 32; ++kk) {
            float4 wa = *(const float4*)(wip + kk * 256);
            float4 wb = *(const float4*)(wjp + kk * 256);
            float2 hh = *(const float2*)&sHi[kc * 32 + kk][0];
            avi[0][0] = fmaf(hh.x, wa.x, avi[0][0]);
            avi[0][1] = fmaf(hh.x, wa.y, avi[0][1]);
            avi[0][2] = fmaf(hh.x, wa.z, avi[0][2]);
            avi[0][3] = fmaf(hh.x, wa.w, avi[0][3]);
            avi[1][0] = fmaf(hh.y, wa.x, avi[1][0]);
            avi[1][1] = fmaf(hh.y, wa.y, avi[1][1]);
            avi[1][2] = fmaf(hh.y, wa.z, avi[1][2]);
            avi[1][3] = fmaf(hh.y, wa.w, avi[1][3]);
            avj[0][0] = fmaf(hh.x, wb.x, avj[0][0]);
            avj[0][1] = fmaf(hh.x, wb.y, avj[0][1]);
            avj[0][2] = fmaf(hh.x, wb.z, avj[0][2]);
            avj[0][3] = fmaf(hh.x, wb.w, avj[0][3]);
            avj[1][0] = fmaf(hh.y, wb.x, avj[1][0]);
            avj[1][1] = fmaf(hh.y, wb.y, avj[1][1]);
            avj[1][2] = fmaf(hh.y, wb.z, avj[1][2]);
            avj[1][3] = fmaf(hh.y, wb.w, avj[1][3]);
        }
        float* pp = &part[kc][jg][0];
#pragma unroll
        for (int c = 0; c < 4; ++c) { pp[c * 2] = avi[0][c]; pp[c * 2 + 1] = avi[1][c]; }
    }
    __syncthreads();
    float vi0 = 0.f, vi1 = 0.f;
    {
        const int m = t >> 2, c = t & 3;
#pragma unroll
        for (int kc = 0; kc < 4; ++kc) {
            vi0 += part[kc][m][c * 2 + 0];
            vi1 += part[kc][m][c * 2 + 1];
        }
    }
    __syncthreads();
    {
        const int kc = t >> 6, jg = t & 63;
        float* pp = &part[kc][jg][0];
#pragma unroll
        for (int c = 0; c < 4; ++c) { pp[c * 2] = avj[0][c]; pp[c * 2 + 1] = avj[1][c]; }
    }
    __syncthreads();
    float vj0, vj1;
    {
        const int m = t >> 2, c = t & 3;
        vj0 = bc1[t]; vj1 = vj0;
#pragma unroll
        for (int kc = 0; kc < 4; ++kc) {
            vj0 += part[kc][m][c * 2 + 0];
            vj1 += part[kc][m][c * 2 + 1];
        }
    }
    fi[i0 * 256 + t] = vi0;
    fi[(i0 + 1) * 256 + t] = vi1;
    fjb[i0 * 256 + t] = vj0;
    fjb[(i0 + 1) * 256 + t] = vj1;
    {
        float su = block_sum(vi0, red), sq = block_sum(vi0 * vi0, red);
        float sv = block_sum(vj0, red), sw = block_sum(vj0 * vj0, red);
        float di = block_sum(vi0 * u, red), dj = block_sum(vj0 * u, red);
        if (t == 0) {
            stats[i0 * 8 + 0] = su * (1.f / 256.f);
            stats[i0 * 8 + 1] = sq * (1.f / 256.f);
            stats[i0 * 8 + 2] = sv * (1.f / 256.f);
            stats[i0 * 8 + 3] = sw * (1.f / 256.f);
            stats[i0 * 8 + 4] = di;
            stats[i0 * 8 + 5] = dj;
        }
        su = block_sum(vi1, red); sq = block_sum(vi1 * vi1, red);
        sv = block_sum(vj1, red); sw = block_sum(vj1 * vj1, red);
        di = block_sum(vi1 * u, red); dj = block_sum(vj1 * u, red);
        if (t == 0) {
            stats[(i0 + 1) * 8 + 0] = su * (1.f / 256.f);
            stats[(i0 + 1) * 8 + 1] = sq * (1.f / 256.f);
            stats[(i0 + 1) * 8 + 2] = sv * (1.f / 256.f);
            stats[(i0 + 1) * 8 + 3] = sw * (1.f / 256.f);
            stats[(i0 + 1) * 8 + 4] = di;
            stats[(i0 + 1) * 8 + 5] = dj;
        }
    }
}

// Per pair (i,j): packed cross-dot -> LN stats -> packed nonlinear pass.
// logits = [rs*(Di+Dj) + c0*Sgw + Sew] - 2*sum_d (y/v)*w' + bc2, where
// y = z*log2e, v = t^2+2t+2, t = 2^y = e^z, w' = wc2*ln2. The linear term
// sum z*wc2 is precomputed per-row in k1. rcp batched 8-wide.
__global__ __launch_bounds__(256, 4) void k3_pair(
    const float* __restrict__ fi, const float* __restrict__ fjb,
    const float* __restrict__ stats, const float* __restrict__ Gp,
    const float* __restrict__ Ep, const float* __restrict__ Wp,
    const float* __restrict__ consts, const float* __restrict__ bc2,
    float* __restrict__ out, int write_mask) {
    __shared__ __align__(16) float FI[16][260];  // 2-way banks on reads (free)
    __shared__ __align__(16) float FJ[16][260];
    __shared__ __align__(16) float Gs[256], Es[256], Ws[256];
    const int tid = threadIdx.x;
    const int i0 = blockIdx.y * 16, j0 = blockIdx.x * 16;
#pragma unroll
    for (int l = 0; l < 4; ++l) {
        int idx = tid + l * 256;
        int r = idx >> 6, c = (idx & 63) * 4;
        *(float4*)&FI[r][c] = *(const float4*)&fi[(i0 + r) * 256 + c];
        *(float4*)&FJ[r][c] = *(const float4*)&fjb[(j0 + r) * 256 + c];
    }
    Gs[tid] = Gp[tid];
    Es[tid] = Ep[tid];
    Ws[tid] = Wp[tid];
    const int ti = tid >> 4, tj = tid & 15;
    const float mi = stats[(i0 + ti) * 8 + 0];
    const float qi = stats[(i0 + ti) * 8 + 1];
    const float Di = stats[(i0 + ti) * 8 + 4];
    const float mj = stats[(j0 + tj) * 8 + 2];
    const float qj = stats[(j0 + tj) * 8 + 3];
    const float Dj = stats[(j0 + tj) * 8 + 5];
    const float Sgw = consts[0], Sew = consts[1], bc2f = bc2[0];
    __syncthreads();
    const float* FIp = &FI[ti][0];
    const float* FJp = &FJ[tj][0];
    // pass 1: dot(fi[i], fjb[j]) for the LN cross term (packed)
    v2f da = {0.f, 0.f}, db = {0.f, 0.f};
#pragma unroll 8
    for (int d8 = 0; d8 < 32; ++d8) {
        v4f xiA = *(const v4f*)(FIp + d8 * 8);
        v4f xiB = *(const v4f*)(FIp + d8 * 8 + 4);
        v4f xjA = *(const v4f*)(FJp + d8 * 8);
        v4f xjB = *(const v4f*)(FJp + d8 * 8 + 4);
        da = pk_fma(LO2(xiA), LO2(xjA), da);
        db = pk_fma(HI2(xiA), HI2(xjA), db);
        da = pk_fma(LO2(xiB), LO2(xjB), da);
        db = pk_fma(HI2(xiB), HI2(xjB), db);
    }
    const float dot = (da.x + da.y) + (db.x + db.y);
    const float m = mi + mj;
    const float ex2 = qi + qj + dot * (2.f / 256.f);
    const float var = fmaxf(ex2 - m * m, 0.f);
    const float rs = __builtin_amdgcn_rsqf(var + EPS);
    const float c0 = -m * rs;
    const float lin = fmaf(rs, Di + Dj, fmaf(c0, Sgw, Sew));
    // pass 2: nonlinear term, 8 elems/iter, one rcp per 8
    const v2f rs2 = {rs, rs}, c02 = {c0, c0}, two2 = {2.f, 2.f};
    v2f accA = {0.f, 0.f}, accB = {0.f, 0.f};
    const v4f* G4 = (const v4f*)&Gs[0];
    const v4f* E4 = (const v4f*)&Es[0];
    const v4f* W4 = (const v4f*)&Ws[0];
#pragma unroll 2
    for (int d8 = 0; d8 < 32; ++d8) {
        v4f xiA = *(const v4f*)(FIp + d8 * 8);
        v4f xiB = *(const v4f*)(FIp + d8 * 8 + 4);
        v4f xjA = *(const v4f*)(FJp + d8 * 8);
        v4f xjB = *(const v4f*)(FJp + d8 * 8 + 4);
        v4f gA = G4[d8 * 2], gB = G4[d8 * 2 + 1];
        v4f eA = E4[d8 * 2], eB = E4[d8 * 2 + 1];
        v4f wA = W4[d8 * 2], wB = W4[d8 * 2 + 1];
        v2f xs0 = pk_add(LO2(xiA), LO2(xjA));
        v2f xs1 = pk_add(HI2(xiA), HI2(xjA));
        v2f xs2 = pk_add(LO2(xiB), LO2(xjB));
        v2f xs3 = pk_add(HI2(xiB), HI2(xjB));
        v2f y0 = pk_fma(pk_fma(xs0, rs2, c02), LO2(gA), LO2(eA));
        v2f y1 = pk_fma(pk_fma(xs1, rs2, c02), HI2(gA), HI2(eA));
        v2f y2 = pk_fma(pk_fma(xs2, rs2, c02), LO2(gB), LO2(eB));
        v2f y3 = pk_fma(pk_fma(xs3, rs2, c02), HI2(gB), HI2(eB));
        v2f t0, t1, t2, t3;
        t0.x = __builtin_amdgcn_exp2f(y0.x); t0.y = __builtin_amdgcn_exp2f(y0.y);
        t1.x = __builtin_amdgcn_exp2f(y1.x); t1.y = __builtin_amdgcn_exp2f(y1.y);
        t2.x = __builtin_amdgcn_exp2f(y2.x); t2.y = __builtin_amdgcn_exp2f(y2.y);
        t3.x = __builtin_amdgcn_exp2f(y3.x); t3.y = __builtin_amdgcn_exp2f(y3.y);
        v2f v0 = pk_fma(t0, pk_add(t0, two2), two2);  // t^2+2t+2 >= 2
        v2f v1 = pk_fma(t1, pk_add(t1, two2), two2);
        v2f v2_ = pk_fma(t2, pk_add(t2, two2), two2);
        v2f v3 = pk_fma(t3, pk_add(t3, two2), two2);
        v2f Pab = pk_mul(v0, v1), Pcd = pk_mul(v2_, v3);
        v2f Q = pk_mul(Pab, Pcd);
        float rall = __builtin_amdgcn_rcpf(Q.x * Q.y);
        v2f R1; R1.x = rall * Q.y; R1.y = rall * Q.x;  // {1/Q.x, 1/Q.y}
        v2f Rab = pk_mul(R1, Pcd), Rcd = pk_mul(R1, Pab);
        v2f i0v = pk_mul(Rab, v1);   // {1/v0.x, 1/v0.y}
        v2f i1v = pk_mul(Rab, v0);
        v2f i2v = pk_mul(Rcd, v3);
        v2f i3v = pk_mul(Rcd, v2_);
        accA = pk_fma(pk_mul(y0, i0v), LO2(wA), accA);
        accB = pk_fma(pk_mul(y1, i1v), HI2(wA), accB);
        accA = pk_fma(pk_mul(y2, i2v), LO2(wB), accA);
        accB = pk_fma(pk_mul(y3, i3v), HI2(wB), accB);
    }
    const float nl = (accA.x + accA.y) + (accB.x + accB.y);
    const int oi = (i0 + ti) * 768 + j0 + tj;
    out[oi] = fmaf(-2.f, nl, lin) + bc2f;
    if (write_mask) out[LOGITS_N + oi] = 1.0f;  // matrix_mask = ones
}

extern "C" void kernel_launch(void* const* d_in, const int* in_sizes, int n_in,
                              void* d_out, int out_size, void* d_ws, size_t ws_size,
                              hipStream_t stream) {
    const float* h   = (const float*)d_in[0];
    const float* W0  = (const float*)d_in[1];
    const float* b0  = (const float*)d_in[2];
    const float* g0  = (const float*)d_in[3];
    const float* be0 = (const float*)d_in[4];
    const float* W1  = (const float*)d_in[5];
    const float* b1  = (const float*)d_in[6];
    const float* Wc1 = (const float*)d_in[7];
    const float* bc1 = (const float*)d_in[8];
    const float* gc  = (const float*)d_in[9];
    const float* bec = (const float*)d_in[10];
    const float* Wc2 = (const float*)d_in[11];
    const float* bc2 = (const float*)d_in[12];
    float* ws = (float*)d_ws;
    float* fi     = ws;             // 768*256
    float* fjb    = ws + 196608;    // 768*256
    float* stats  = ws + 393216;    // 768*8
    float* Gp     = ws + 399360;    // 256
    float* Ep     = ws + 399616;    // 256
    float* Wp     = ws + 399872;    // 256
    float* consts = ws + 400128;    // 2
    float* out = (float*)d_out;
    int write_mask = (out_size >= 2 * LOGITS_N) ? 1 : 0;

    k1_rows<<<dim3(384), dim3(256), 0, stream>>>(h, W0, b0, g0, be0, W1, b1,
                                                 Wc1, bc1, gc, bec, Wc2,
                                                 fi, fjb, stats, Gp, Ep, Wp,
                                                 consts);
    k3_pair<<<dim3(48, 48), dim3(256), 0, stream>>>(fi, fjb, stats, Gp, Ep, Wp,
                                                    consts, bc2, out, write_mask);
}

// Round 8
// 67.125 us; speedup vs baseline: 1.5751x; 1.0153x over previous
//
#include <hip/hip_runtime.h>

#define EPS 1e-5f
#define LOGITS_N (768 * 768)
#define LOG2E 1.4426950408889634f
#define LN2   0.6931471805599453f

typedef float v2f __attribute__((ext_vector_type(2)));
typedef float v4f __attribute__((ext_vector_type(4)));

// Packed fp32 ops (VOP3P) via inline asm.
__device__ __forceinline__ v2f pk_add(v2f a, v2f b) {
    v2f d; asm("v_pk_add_f32 %0, %1, %2" : "=v"(d) : "v"(a), "v"(b)); return d;
}
__device__ __forceinline__ v2f pk_mul(v2f a, v2f b) {
    v2f d; asm("v_pk_mul_f32 %0, %1, %2" : "=v"(d) : "v"(a), "v"(b)); return d;
}
__device__ __forceinline__ v2f pk_fma(v2f a, v2f b, v2f c) {
    v2f d; asm("v_pk_fma_f32 %0, %1, %2, %3" : "=v"(d) : "v"(a), "v"(b), "v"(c)); return d;
}
#define LO2(v) __builtin_shufflevector(v, v, 0, 1)
#define HI2(v) __builtin_shufflevector(v, v, 2, 3)

// mish(z) = z * tanh(softplus(z)); with t = e^z: mish = z*u/(u+2), u = t(t+2)
__device__ __forceinline__ float mishf(float z) {
    float t = __expf(fminf(z, 40.f));
    float u = t * (t + 2.f);
    return z * u * __builtin_amdgcn_rcpf(u + 2.f);
}

// block of 256 threads (4 waves); returns full sum to all threads
__device__ __forceinline__ float block_sum(float v, float* red) {
#pragma unroll
    for (int off = 32; off > 0; off >>= 1) v += __shfl_down(v, off, 64);
    const int lane = threadIdx.x & 63, wid = threadIdx.x >> 6;
    __syncthreads();
    if (lane == 0) red[wid] = v;
    __syncthreads();
    return red[0] + red[1] + red[2] + red[3];
}

// 2 rows per block (384 blocks). Coalesced float4 weight loads via k-split.
// Outputs CENTERED rows: fi = vi - mean(vi), fjb = (vj+bc1) - mean(vj+bc1),
// plus per-row D' = dot(centered, gc.*wc2). k3's pair variance is then just
// mean((fic+fjc)^2) -- computed in k3's pass 1 with no cross term at all.
__global__ __launch_bounds__(256) void k1_rows(
    const float* __restrict__ h, const float* __restrict__ W0,
    const float* __restrict__ b0, const float* __restrict__ g0,
    const float* __restrict__ be0, const float* __restrict__ W1,
    const float* __restrict__ b1, const float* __restrict__ Wc1,
    const float* __restrict__ bc1, const float* __restrict__ gc,
    const float* __restrict__ bec, const float* __restrict__ wc2,
    float* __restrict__ fi, float* __restrict__ fjb,
    float* __restrict__ stats, float* __restrict__ Gp,
    float* __restrict__ Ep, float* __restrict__ Wp,
    float* __restrict__ consts) {
    __shared__ float shi[256][2];
    __shared__ float sai[256][2];
    __shared__ float sHi[128][2];
    __shared__ float red[4];
    __shared__ float part[4][64][12];
    const int t = threadIdx.x;
    const int i0 = blockIdx.x * 2;
    const float u = gc[t] * wc2[t];
    if (blockIdx.x == 0) {
        Gp[t] = gc[t] * LOG2E;
        Ep[t] = bec[t] * LOG2E;
        Wp[t] = wc2[t] * LN2;
        float sew = block_sum(bec[t] * wc2[t], red);
        if (t == 0) { consts[0] = sew; }
    }
    shi[t][0] = h[i0 * 256 + t];
    shi[t][1] = h[i0 * 256 + 256 + t];
    __syncthreads();
    // ---- GEMM1: x[2][256] = h2 @ W0   (k-split 4 x 64, cols 4/thread) ----
    {
        const int kc = t >> 6, jg = t & 63;
        const float* w0p = W0 + (kc * 64) * 256 + jg * 4;
        float ax[2][4] = {};
#pragma unroll 8
        for (int kk = 0; kk < 64; ++kk) {
            float4 w = *(const float4*)(w0p + kk * 256);
            float2 hh = *(const float2*)&shi[kc * 64 + kk][0];
            ax[0][0] = fmaf(hh.x, w.x, ax[0][0]);
            ax[0][1] = fmaf(hh.x, w.y, ax[0][1]);
            ax[0][2] = fmaf(hh.x, w.z, ax[0][2]);
            ax[0][3] = fmaf(hh.x, w.w, ax[0][3]);
            ax[1][0] = fmaf(hh.y, w.x, ax[1][0]);
            ax[1][1] = fmaf(hh.y, w.y, ax[1][1]);
            ax[1][2] = fmaf(hh.y, w.z, ax[1][2]);
            ax[1][3] = fmaf(hh.y, w.w, ax[1][3]);
        }
        float* pp = &part[kc][jg][0];
#pragma unroll
        for (int c = 0; c < 4; ++c) { pp[c * 2] = ax[0][c]; pp[c * 2 + 1] = ax[1][c]; }
    }
    __syncthreads();
    float x0, x1;
    {
        const int m = t >> 2, c = t & 3;
        x0 = b0[t]; x1 = x0;
#pragma unroll
        for (int kc = 0; kc < 4; ++kc) {
            x0 += part[kc][m][c * 2 + 0];
            x1 += part[kc][m][c * 2 + 1];
        }
    }
    // ---- LN + mish per row ----
    {
        float s1 = block_sum(x0, red), s2 = block_sum(x0 * x0, red);
        float mean = s1 * (1.f / 256.f);
        float var = fmaxf(s2 * (1.f / 256.f) - mean * mean, 0.f);
        float rs = __builtin_amdgcn_rsqf(var + EPS);
        sai[t][0] = mishf((x0 - mean) * rs * g0[t] + be0[t]);
        s1 = block_sum(x1, red); s2 = block_sum(x1 * x1, red);
        mean = s1 * (1.f / 256.f);
        var = fmaxf(s2 * (1.f / 256.f) - mean * mean, 0.f);
        rs = __builtin_amdgcn_rsqf(var + EPS);
        sai[t][1] = mishf((x1 - mean) * rs * g0[t] + be0[t]);
    }
    __syncthreads();
    // ---- GEMM2: H[2][128] = a2 @ W1   (k-split 8 x 32, cols 4/thread) ----
    {
        const int kc = t >> 5, jg = t & 31;
        const float* w1p = W1 + (kc * 32) * 128 + jg * 4;
        float ah[2][4] = {};
#pragma unroll 8
        for (int kk = 0; kk < 32; ++kk) {
            float4 w = *(const float4*)(w1p + kk * 128);
            float2 ss = *(const float2*)&sai[kc * 32 + kk][0];
            ah[0][0] = fmaf(ss.x, w.x, ah[0][0]);
            ah[0][1] = fmaf(ss.x, w.y, ah[0][1]);
            ah[0][2] = fmaf(ss.x, w.z, ah[0][2]);
            ah[0][3] = fmaf(ss.x, w.w, ah[0][3]);
            ah[1][0] = fmaf(ss.y, w.x, ah[1][0]);
            ah[1][1] = fmaf(ss.y, w.y, ah[1][1]);
            ah[1][2] = fmaf(ss.y, w.z, ah[1][2]);
            ah[1][3] = fmaf(ss.y, w.w, ah[1][3]);
        }
        float* pp = &part[0][0][0] + (kc * 32 + jg) * 12;
#pragma unroll
        for (int c = 0; c < 4; ++c) { pp[c * 2] = ah[0][c]; pp[c * 2 + 1] = ah[1][c]; }
    }
    __syncthreads();
    {
        const int r = t >> 7, jj = t & 127;
        float hv = b1[jj];
        const float* pf = &part[0][0][0];
#pragma unroll
        for (int kc = 0; kc < 8; ++kc)
            hv += pf[(kc * 32 + (jj >> 2)) * 12 + (jj & 3) * 2 + r];
        sHi[jj][r] = hv;
    }
    __syncthreads();
    // ---- GEMM3: vi = H@Wi, vj = H@Wj (K=128, k-split 4 x 32) ----
    float avi[2][4] = {}, avj[2][4] = {};
    {
        const int kc = t >> 6, jg = t & 63;
        const float* wip = Wc1 + (kc * 32) * 256 + jg * 4;
        const float* wjp = Wc1 + (128 + kc * 32) * 256 + jg * 4;
#pragma unroll 4
        for (int kk = 0; kk < 32; ++kk) {
            float4 wa = *(const float4*)(wip + kk * 256);
            float4 wb = *(const float4*)(wjp + kk * 256);
            float2 hh = *(const float2*)&sHi[kc * 32 + kk][0];
            avi[0][0] = fmaf(hh.x, wa.x, avi[0][0]);
            avi[0][1] = fmaf(hh.x, wa.y, avi[0][1]);
            avi[0][2] = fmaf(hh.x, wa.z, avi[0][2]);
            avi[0][3] = fmaf(hh.x, wa.w, avi[0][3]);
            avi[1][0] = fmaf(hh.y, wa.x, avi[1][0]);
            avi[1][1] = fmaf(hh.y, wa.y, avi[1][1]);
            avi[1][2] = fmaf(hh.y, wa.z, avi[1][2]);
            avi[1][3] = fmaf(hh.y, wa.w, avi[1][3]);
            avj[0][0] = fmaf(hh.x, wb.x, avj[0][0]);
            avj[0][1] = fmaf(hh.x, wb.y, avj[0][1]);
            avj[0][2] = fmaf(hh.x, wb.z, avj[0][2]);
            avj[0][3] = fmaf(hh.x, wb.w, avj[0][3]);
            avj[1][0] = fmaf(hh.y, wb.x, avj[1][0]);
            avj[1][1] = fmaf(hh.y, wb.y, avj[1][1]);
            avj[1][2] = fmaf(hh.y, wb.z, avj[1][2]);
            avj[1][3] = fmaf(hh.y, wb.w, avj[1][3]);
        }
        float* pp = &part[kc][jg][0];
#pragma unroll
        for (int c = 0; c < 4; ++c) { pp[c * 2] = avi[0][c]; pp[c * 2 + 1] = avi[1][c]; }
    }
    __syncthreads();
    float vi0 = 0.f, vi1 = 0.f;
    {
        const int m = t >> 2, c = t & 3;
#pragma unroll
        for (int kc = 0; kc < 4; ++kc) {
            vi0 += part[kc][m][c * 2 + 0];
            vi1 += part[kc][m][c * 2 + 1];
        }
    }
    __syncthreads();
    {
        const int kc = t >> 6, jg = t & 63;
        float* pp = &part[kc][jg][0];
#pragma unroll
        for (int c = 0; c < 4; ++c) { pp[c * 2] = avj[0][c]; pp[c * 2 + 1] = avj[1][c]; }
    }
    __syncthreads();
    float vj0, vj1;
    {
        const int m = t >> 2, c = t & 3;
        vj0 = bc1[t]; vj1 = vj0;
#pragma unroll
        for (int kc = 0; kc < 4; ++kc) {
            vj0 += part[kc][m][c * 2 + 0];
            vj1 += part[kc][m][c * 2 + 1];
        }
    }
    // ---- Center rows, write centered arrays + per-row D' stats ----
    {
        float su = block_sum(vi0, red);
        float fc = vi0 - su * (1.f / 256.f);
        fi[i0 * 256 + t] = fc;
        float d = block_sum(fc * u, red);
        float sv = block_sum(vj0, red);
        float gcj = vj0 - sv * (1.f / 256.f);
        fjb[i0 * 256 + t] = gcj;
        float dj = block_sum(gcj * u, red);
        if (t == 0) {
            stats[i0 * 8 + 1] = d;
            stats[i0 * 8 + 3] = dj;
        }
        su = block_sum(vi1, red);
        fc = vi1 - su * (1.f / 256.f);
        fi[(i0 + 1) * 256 + t] = fc;
        d = block_sum(fc * u, red);
        sv = block_sum(vj1, red);
        gcj = vj1 - sv * (1.f / 256.f);
        fjb[(i0 + 1) * 256 + t] = gcj;
        dj = block_sum(gcj * u, red);
        if (t == 0) {
            stats[(i0 + 1) * 8 + 1] = d;
            stats[(i0 + 1) * 8 + 3] = dj;
        }
    }
}

// 8-elem packed mish+dot body; xc = fic+fjc is already centered, so
// y = (xc*rs)*G' + E'. One rcp per 8 elems (v >= 2 always; overflow would
// need sum of positive z > 44 across 8 LN'd elems -- impossible).
#define MISH8(XJP, RS2, ACC0, ACC1)                                          \
    do {                                                                      \
        v4f xjA = *(const v4f*)(XJP);                                         \
        v4f xjB = *(const v4f*)((XJP) + 4);                                   \
        v2f xs0 = pk_add(LO2(xiA), LO2(xjA));                                 \
        v2f xs1 = pk_add(HI2(xiA), HI2(xjA));                                 \
        v2f xs2 = pk_add(LO2(xiB), LO2(xjB));                                 \
        v2f xs3 = pk_add(HI2(xiB), HI2(xjB));                                 \
        v2f y0 = pk_fma(pk_mul(xs0, RS2), LO2(gA), LO2(eA));                  \
        v2f y1 = pk_fma(pk_mul(xs1, RS2), HI2(gA), HI2(eA));                  \
        v2f y2 = pk_fma(pk_mul(xs2, RS2), LO2(gB), LO2(eB));                  \
        v2f y3 = pk_fma(pk_mul(xs3, RS2), HI2(gB), HI2(eB));                  \
        v2f t0, t1, t2, t3;                                                   \
        t0.x = __builtin_amdgcn_exp2f(y0.x); t0.y = __builtin_amdgcn_exp2f(y0.y); \
        t1.x = __builtin_amdgcn_exp2f(y1.x); t1.y = __builtin_amdgcn_exp2f(y1.y); \
        t2.x = __builtin_amdgcn_exp2f(y2.x); t2.y = __builtin_amdgcn_exp2f(y2.y); \
        t3.x = __builtin_amdgcn_exp2f(y3.x); t3.y = __builtin_amdgcn_exp2f(y3.y); \
        v2f v0 = pk_fma(t0, pk_add(t0, two2), two2);                          \
        v2f v1 = pk_fma(t1, pk_add(t1, two2), two2);                          \
        v2f v2_ = pk_fma(t2, pk_add(t2, two2), two2);                         \
        v2f v3 = pk_fma(t3, pk_add(t3, two2), two2);                          \
        v2f Pab = pk_mul(v0, v1), Pcd = pk_mul(v2_, v3);                      \
        v2f Q = pk_mul(Pab, Pcd);                                             \
        float rall = __builtin_amdgcn_rcpf(Q.x * Q.y);                        \
        v2f R1; R1.x = rall * Q.y; R1.y = rall * Q.x;                         \
        v2f Rab = pk_mul(R1, Pcd), Rcd = pk_mul(R1, Pab);                     \
        v2f iv0 = pk_mul(Rab, v1);                                            \
        v2f iv1 = pk_mul(Rab, v0);                                            \
        v2f iv2 = pk_mul(Rcd, v3);                                            \
        v2f iv3 = pk_mul(Rcd, v2_);                                           \
        ACC0 = pk_fma(pk_mul(y0, iv0), LO2(wA), ACC0);                        \
        ACC1 = pk_fma(pk_mul(y1, iv1), HI2(wA), ACC1);                        \
        ACC0 = pk_fma(pk_mul(y2, iv2), LO2(wB), ACC0);                        \
        ACC1 = pk_fma(pk_mul(y3, iv3), HI2(wB), ACC1);                        \
    } while (0)

// Validated 16x16 tile, 48x48 grid, 1 pair/thread, all operands from LDS.
// Pass 1: var = mean((fic+fjc)^2) -- perfectly conditioned, NO cross term.
// Pass 2: logits = rs*(Di+Dj) + Sew - 2*sum_d (y/v)*w' + bc2.
__global__ __launch_bounds__(256, 4) void k3_pair(
    const float* __restrict__ fi, const float* __restrict__ fjb,
    const float* __restrict__ stats,
    const float* __restrict__ Gp, const float* __restrict__ Ep,
    const float* __restrict__ Wp, const float* __restrict__ consts,
    const float* __restrict__ bc2, float* __restrict__ out, int write_mask) {
    __shared__ __align__(16) float FI[16][260];  // 2-way banks on reads (free)
    __shared__ __align__(16) float FJ[16][260];
    __shared__ __align__(16) float Gs[256], Es[256], Ws[256];
    const int tid = threadIdx.x;
    const int i0 = blockIdx.y * 16, j0 = blockIdx.x * 16;
#pragma unroll
    for (int l = 0; l < 4; ++l) {
        int idx = tid + l * 256;
        int r = idx >> 6, c = (idx & 63) * 4;
        *(float4*)&FI[r][c] = *(const float4*)&fi[(i0 + r) * 256 + c];
        *(float4*)&FJ[r][c] = *(const float4*)&fjb[(j0 + r) * 256 + c];
    }
    Gs[tid] = Gp[tid];
    Es[tid] = Ep[tid];
    Ws[tid] = Wp[tid];
    const int ti = tid >> 4, tj = tid & 15;
    const int i = i0 + ti, j = j0 + tj;
    const float Di = stats[i * 8 + 1];
    const float Dj = stats[j * 8 + 3];
    const float Sew = consts[0], bc2f = bc2[0];
    __syncthreads();
    const float* FIp = &FI[ti][0];
    const float* FJp = &FJ[tj][0];
    // pass 1: var = mean((fic+fjc)^2)  (sum of squares -> no cancellation)
    v2f sqa = {0.f, 0.f}, sqb = {0.f, 0.f};
#pragma unroll 8
    for (int d8 = 0; d8 < 32; ++d8) {
        v4f xiA = *(const v4f*)(FIp + d8 * 8);
        v4f xiB = *(const v4f*)(FIp + d8 * 8 + 4);
        v4f xjA = *(const v4f*)(FJp + d8 * 8);
        v4f xjB = *(const v4f*)(FJp + d8 * 8 + 4);
        v2f s0 = pk_add(LO2(xiA), LO2(xjA));
        v2f s1 = pk_add(HI2(xiA), HI2(xjA));
        v2f s2 = pk_add(LO2(xiB), LO2(xjB));
        v2f s3 = pk_add(HI2(xiB), HI2(xjB));
        sqa = pk_fma(s0, s0, sqa);
        sqb = pk_fma(s1, s1, sqb);
        sqa = pk_fma(s2, s2, sqa);
        sqb = pk_fma(s3, s3, sqb);
    }
    const float var = ((sqa.x + sqa.y) + (sqb.x + sqb.y)) * (1.f / 256.f);
    const float rs = __builtin_amdgcn_rsqf(var + EPS);
    const float lin = fmaf(rs, Di + Dj, Sew);
    // pass 2: nonlinear term
    const v4f* G4 = (const v4f*)&Gs[0];
    const v4f* E4 = (const v4f*)&Es[0];
    const v4f* W4 = (const v4f*)&Ws[0];
    const v2f rs2 = {rs, rs};
    const v2f two2 = {2.f, 2.f};
    v2f acc0 = {0.f, 0.f}, acc1 = {0.f, 0.f};
#pragma unroll 2
    for (int d8 = 0; d8 < 32; ++d8) {
        v4f xiA = *(const v4f*)(FIp + d8 * 8);
        v4f xiB = *(const v4f*)(FIp + d8 * 8 + 4);
        v4f gA = G4[d8 * 2], gB = G4[d8 * 2 + 1];
        v4f eA = E4[d8 * 2], eB = E4[d8 * 2 + 1];
        v4f wA = W4[d8 * 2], wB = W4[d8 * 2 + 1];
        MISH8(FJp + d8 * 8, rs2, acc0, acc1);
    }
    const float nl = (acc0.x + acc0.y) + (acc1.x + acc1.y);
    out[i * 768 + j] = fmaf(-2.f, nl, lin) + bc2f;
    if (write_mask) out[LOGITS_N + i * 768 + j] = 1.0f;
}

extern "C" void kernel_launch(void* const* d_in, const int* in_sizes, int n_in,
                              void* d_out, int out_size, void* d_ws, size_t ws_size,
                              hipStream_t stream) {
    const float* h   = (const float*)d_in[0];
    const float* W0  = (const float*)d_in[1];
    const float* b0  = (const float*)d_in[2];
    const float* g0  = (const float*)d_in[3];
    const float* be0 = (const float*)d_in[4];
    const float* W1  = (const float*)d_in[5];
    const float* b1  = (const float*)d_in[6];
    const float* Wc1 = (const float*)d_in[7];
    const float* bc1 = (const float*)d_in[8];
    const float* gc  = (const float*)d_in[9];
    const float* bec = (const float*)d_in[10];
    const float* Wc2 = (const float*)d_in[11];
    const float* bc2 = (const float*)d_in[12];
    float* ws = (float*)d_ws;
    float* fi     = ws;             // 768*256
    float* fjb    = ws + 196608;    // 768*256
    float* stats  = ws + 393216;    // 768*8
    float* Gp     = ws + 399360;    // 256
    float* Ep     = ws + 399616;    // 256
    float* Wp     = ws + 399872;    // 256
    float* consts = ws + 400128;    // 4
    float* out = (float*)d_out;
    int write_mask = (out_size >= 2 * LOGITS_N) ? 1 : 0;

    k1_rows<<<dim3(384), dim3(256), 0, stream>>>(h, W0, b0, g0, be0, W1, b1,
                                                 Wc1, bc1, gc, bec, Wc2,
                                                 fi, fjb, stats, Gp, Ep, Wp,
                                                 consts);
    k3_pair<<<dim3(48, 48), dim3(256), 0, stream>>>(fi, fjb, stats,
                                                    Gp, Ep, Wp, consts, bc2,
                                                    out, write_mask);
}